// Round 4
// baseline (148.695 us; speedup 1.0000x reference)
//
#include <hip/hip_runtime.h>

// Paillier sum-pooling = windowed modular product of ciphertexts mod n^2.
// M = NSQ = 46337^2 = 2147117569 < 2^31; inputs int32, output int32 (exact).
//
// Memory-bound: 537 MB read + 134 MB write (~107 us floor at 6.3 TB/s).
// Cheap exact mod via 2^31 = M + 366079:  p mod M folds as
//   p -> (p>>31)*366079 + (p & 0x7FFFFFFF)
// bound chain 2^62 -> 2^49.6 -> 2^37.1 -> <= 2170912703 (< 2M), closed under
// chaining (inputs < 2.171e9 -> product < 2^62.04), one final cond-subtract.

#define M   2147117569u
#define K31 366079ull          // 2^31 mod M

typedef int int4v __attribute__((ext_vector_type(4)));

// Partial modular multiply: a,b <= 2170912703; returns s ≡ a*b (mod M),
// s <= 2170912703. Exact integer arithmetic throughout.
__device__ __forceinline__ unsigned modmul31(unsigned a, unsigned b) {
    unsigned long long p = (unsigned long long)a * b;                                  // < 2^62.04
    p = (unsigned long long)(unsigned)(p >> 31) * K31 + (unsigned)(p & 0x7FFFFFFF);    // < 2^49.6
    p = (unsigned long long)(unsigned)(p >> 31) * K31 + (unsigned)(p & 0x7FFFFFFF);    // < 2^37.1
    p = (unsigned long long)(unsigned)(p >> 31) * K31 + (unsigned)(p & 0x7FFFFFFF);    // <= 2170912703
    return (unsigned)p;
}

__global__ __launch_bounds__(256) void paillier_pool_kernel(
    const int* __restrict__ x, int* __restrict__ out, int nwork)
{
    const int stride = gridDim.x * blockDim.x;               // 524288
    for (int wi = blockIdx.x * blockDim.x + threadIdx.x; wi < nwork; wi += stride) {
        // Each work item produces 8 consecutive-in-c outputs (c8-aligned, 64%8==0).
        int flat = wi << 3;              // output flat index ((b*128+ho)*128+wo)*64+c
        int c  = flat & 63;
        int wo = (flat >> 6) & 127;
        int ho = (flat >> 13) & 127;
        int b  = flat >> 20;

        // input flat index: ((b*256 + 2*ho)*256 + 2*wo)*64 + c  (< 2^27, fits int)
        int base = ((((b << 8) + (ho << 1)) << 8) + (wo << 1)) * 64 + c;

        int4v v00a = __builtin_nontemporal_load((const int4v*)(x + base));
        int4v v00b = __builtin_nontemporal_load((const int4v*)(x + base + 4));
        int4v v01a = __builtin_nontemporal_load((const int4v*)(x + base + 64));
        int4v v01b = __builtin_nontemporal_load((const int4v*)(x + base + 68));
        int4v v10a = __builtin_nontemporal_load((const int4v*)(x + base + 16384));
        int4v v10b = __builtin_nontemporal_load((const int4v*)(x + base + 16388));
        int4v v11a = __builtin_nontemporal_load((const int4v*)(x + base + 16448));
        int4v v11b = __builtin_nontemporal_load((const int4v*)(x + base + 16452));

        int4v ra, rb;
#pragma unroll
        for (int k = 0; k < 4; ++k) {
            unsigned t0 = modmul31((unsigned)v00a[k], (unsigned)v01a[k]);
            unsigned t1 = modmul31((unsigned)v10a[k], (unsigned)v11a[k]);
            unsigned t  = modmul31(t0, t1);
            if (t >= M) t -= M;
            ra[k] = (int)t;

            unsigned u0 = modmul31((unsigned)v00b[k], (unsigned)v01b[k]);
            unsigned u1 = modmul31((unsigned)v10b[k], (unsigned)v11b[k]);
            unsigned u  = modmul31(u0, u1);
            if (u >= M) u -= M;
            rb[k] = (int)u;
        }

        __builtin_nontemporal_store(ra, (int4v*)(out + flat));
        __builtin_nontemporal_store(rb, (int4v*)(out + flat + 4));
    }
}

extern "C" void kernel_launch(void* const* d_in, const int* in_sizes, int n_in,
                              void* d_out, int out_size, void* d_ws, size_t ws_size,
                              hipStream_t stream) {
    const int* x = (const int*)d_in[0];
    int* out = (int*)d_out;

    const int nwork = out_size / 8;      // 33554432 / 8 = 4194304
    const int block = 256;
    const int grid  = 2048;              // 8 blocks/CU, grid-stride x8 iterations

    paillier_pool_kernel<<<grid, block, 0, stream>>>(x, out, nwork);
}

// Round 5
// 116.479 us; speedup vs baseline: 1.2766x; 1.2766x over previous
//
#include <hip/hip_runtime.h>

// Paillier sum-pooling = windowed modular product of ciphertexts mod n^2.
// M = NSQ = 46337^2 = 2147117569 < 2^31; inputs int32, output int32 (exact).
//
// Memory-bound: 537 MB read + 134 MB write (~107 us floor at 6.3 TB/s).
// Round-3 memory structure (4 outputs/thread, per-instruction contiguous
// int4 loads — 64 lanes x 16 B, perfectly coalesced) + cheap exact mod:
// 2^31 = M + 366079, so  p mod M folds as p -> (p>>31)*366079 + (p&0x7FFFFFFF).
// Bound chain: 2^62.04 -> 2^49.6 -> 2^37.1 -> <= 2170912703 < 2M, closed under
// chaining; single conditional subtract at the end.

#define M   2147117569u
#define K31 366079ull          // 2^31 mod M

typedef int int4v __attribute__((ext_vector_type(4)));

// Partial modular multiply: a,b <= 2170912703; returns s ≡ a*b (mod M),
// s <= 2170912703. Exact integer arithmetic throughout.
__device__ __forceinline__ unsigned modmul31(unsigned a, unsigned b) {
    unsigned long long p = (unsigned long long)a * b;                                  // < 2^62.04
    p = (unsigned long long)(unsigned)(p >> 31) * K31 + (unsigned)(p & 0x7FFFFFFF);    // < 2^49.6
    p = (unsigned long long)(unsigned)(p >> 31) * K31 + (unsigned)(p & 0x7FFFFFFF);    // < 2^37.1
    p = (unsigned long long)(unsigned)(p >> 31) * K31 + (unsigned)(p & 0x7FFFFFFF);    // <= 2170912703
    return (unsigned)p;
}

__global__ __launch_bounds__(256) void paillier_pool_kernel(
    const int* __restrict__ x, int* __restrict__ out, int nwork)
{
    const int stride = gridDim.x * blockDim.x;               // 524288
    for (int wi = blockIdx.x * blockDim.x + threadIdx.x; wi < nwork; wi += stride) {
        // Each work item produces 4 consecutive-in-c outputs.
        int flat = wi << 2;              // output flat index ((b*128+ho)*128+wo)*64+c
        int c  = flat & 63;
        int wo = (flat >> 6) & 127;
        int ho = (flat >> 13) & 127;
        int b  = flat >> 20;

        // input flat index: ((b*256 + 2*ho)*256 + 2*wo)*64 + c  (< 2^27, fits int)
        int base = ((((b << 8) + (ho << 1)) << 8) + (wo << 1)) * 64 + c;

        int4v v00 = __builtin_nontemporal_load((const int4v*)(x + base));
        int4v v01 = __builtin_nontemporal_load((const int4v*)(x + base + 64));
        int4v v10 = __builtin_nontemporal_load((const int4v*)(x + base + 16384));
        int4v v11 = __builtin_nontemporal_load((const int4v*)(x + base + 16448));

        int4v r;
#pragma unroll
        for (int k = 0; k < 4; ++k) {
            unsigned t0 = modmul31((unsigned)v00[k], (unsigned)v01[k]);
            unsigned t1 = modmul31((unsigned)v10[k], (unsigned)v11[k]);
            unsigned t  = modmul31(t0, t1);
            if (t >= M) t -= M;
            r[k] = (int)t;
        }

        __builtin_nontemporal_store(r, (int4v*)(out + flat));
    }
}

extern "C" void kernel_launch(void* const* d_in, const int* in_sizes, int n_in,
                              void* d_out, int out_size, void* d_ws, size_t ws_size,
                              hipStream_t stream) {
    const int* x = (const int*)d_in[0];
    int* out = (int*)d_out;

    const int nwork = out_size / 4;      // 33554432 / 4 = 8388608
    const int block = 256;
    const int grid  = 2048;              // 8 blocks/CU, grid-stride x16 iterations

    paillier_pool_kernel<<<grid, block, 0, stream>>>(x, out, nwork);
}